// Round 16
// baseline (127.797 us; speedup 1.0000x reference)
//
#include <hip/hip_runtime.h>
#include <hip/hip_bf16.h>

typedef unsigned short u16;
typedef __bf16 bf16x8 __attribute__((ext_vector_type(8)));
typedef float f32x4 __attribute__((ext_vector_type(4)));
typedef float f32x16 __attribute__((ext_vector_type(16)));
typedef unsigned short ushort8 __attribute__((ext_vector_type(8)));

#define C_IN   128
#define C_OUT  256
#define BATCH  16
#define LEN    4096
#define KS     9
#define PAD    4
#define KTOT   (C_IN * KS)        // 1152
#define NSTEP  72                 // K = 1152 / 16

#define W5_BLKS    1152           // 294912 / 256
#define EB_BLKS    256

__device__ inline u16 f2bf(float f) {
    __hip_bfloat16 h = __float2bfloat16(f);
    return __builtin_bit_cast(u16, h);
}

// ---------------------------------------------------------------------------
// Prep (small, one launch):
//  blocks [0,1152): weight -> w5 in 32-lane fragment order for
//    mfma_f32_32x32x16_bf16:  i = ((s*8 + g)*64 + lane)*8 + e  where
//    o = g*32 + (lane&31), hi = lane>>5, c = (s&7)*16 + hi*8 + e, k = s>>3.
//  blocks [1152,1408): ebias[o] = bias[o] + sum offset*W; block 1152: phys.
// ---------------------------------------------------------------------------
__global__ void prep_all(const float* __restrict__ w,
                         const float* __restrict__ bias, const float* __restrict__ vel,
                         const float* __restrict__ acc_in,
                         u16* __restrict__ w5,
                         float* __restrict__ ebias, float* __restrict__ phys_out) {
    int bid = blockIdx.x;
    int t = threadIdx.x;
    if (bid < W5_BLKS) {
        int i = bid * 256 + t;               // 294912 total
        int e    = i & 7;
        int lane = (i >> 3) & 63;
        int g    = (i >> 9) & 7;
        int s    = i >> 12;                  // 0..71
        int o    = g * 32 + (lane & 31);
        int hi   = lane >> 5;
        int c    = (s & 7) * 16 + hi * 8 + e;
        int k    = s >> 3;
        w5[i] = f2bf(w[((size_t)o * C_IN + c) * KS + k]);
        return;
    }
    __shared__ float red[256];
    int o = bid - W5_BLKS;
    float sum = 0.f;
    for (int i = t; i < KTOT; i += 256) {
        int k = i % KS;                    // offset layout [c][k]
        float tk = k * 0.01f;              // DT
        float off = vel[i] * tk + 0.5f * acc_in[i] * tk * tk;
        sum += off * w[(size_t)o * KTOT + i];
    }
    red[t] = sum;
    __syncthreads();
    for (int h = 128; h > 0; h >>= 1) {
        if (t < h) red[t] += red[t + h];
        __syncthreads();
    }
    if (t == 0) ebias[o] = bias[o] + red[0];

    if (o == 0) {                          // phys
        __syncthreads();
        float pv = 0.f;
        for (int i = t; i < KTOT; i += 256) {
            float v = vel[i], a = acc_in[i];
            pv += v * v + a * a;
        }
        red[t] = pv;
        __syncthreads();
        for (int h = 128; h > 0; h >>= 1) {
            if (t < h) red[t] += red[t + h];
            __syncthreads();
        }
        if (t == 0) *phys_out = 0.01f * (red[0] / (float)KTOT);
    }
}

// ---------------------------------------------------------------------------
// Main: R15 (fused-transpose fat-wave, total 51.8us best) with ONE change:
// the K-loop is ROLLED (#pragma unroll 1, 2-step body) instead of fully
// unrolled. Theory: the unrolled ~17-20KB straight-line body is executed
// once per block -> every instruction is an I-cache cold miss streamed from
// L2; MFMA-dense code at ~8cyc/inst outruns sequential I-fetch. An I-fetch
// stall is invisible in MfmaUtil/VALUBusy/vmcnt - matching our ~880cyc/step
// unexplained term that survived every data-path fix (R12/R13/R14).
// Rolled body ~60 insts = I-cache resident. Named even/odd register pairs
// rotate (no runtime-indexed arrays -> no scratch, rule #20 safe).
// Everything else byte-identical to R15.
// ---------------------------------------------------------------------------
__global__ __launch_bounds__(128, 1) void conv_main(const float* __restrict__ x,
                                                    const u16* __restrict__ w5,
                                                    const float* __restrict__ ebias,
                                                    float* __restrict__ out) {
    __shared__ u16 ldsx[17408];            // B tile: 136 rows x 256B = 34816 B

    int b     = blockIdx.y;
    int lbase = blockIdx.x * 128;
    int t     = threadIdx.x;               // 0..127
    int lane  = t & 63;
    int wm    = t >> 6;                    // wave = o-half (128 o each)
    int l31   = lane & 31;
    int hi    = lane >> 5;

    // A source: wave wm's 4 o-groups (g = wm*4+mi) -> contiguous 4KB/step
    const u16* alane = w5 + ((size_t)(wm * 4) * 64 + lane) * 8;

    #define LOAD_A(S, AF)                                                        \
        {                                                                        \
            const u16* p_ = alane + (size_t)(S) * 4096;                          \
            _Pragma("unroll")                                                    \
            for (int mi = 0; mi < 4; ++mi)                                       \
                AF[mi] = *reinterpret_cast<const bf16x8*>(p_ + mi * 512);        \
        }
    #define LOAD_B(S, BF)                                                        \
        {                                                                        \
            int k_ = (S) >> 3;                                                   \
            int sl_ = ((S) & 7) * 2 + hi;                                        \
            _Pragma("unroll")                                                    \
            for (int nj = 0; nj < 4; ++nj) {                                     \
                int row_  = nj * 32 + l31 + k_;                                  \
                int addr_ = row_ * 256 + ((sl_ ^ (row_ & 15)) << 4);             \
                BF[nj] = *reinterpret_cast<const bf16x8*>(ldsbase + addr_);      \
            }                                                                    \
        }
    #define MFMA16(AF, BF)                                                       \
        {                                                                        \
            _Pragma("unroll")                                                    \
            for (int mi = 0; mi < 4; ++mi)                                       \
                _Pragma("unroll")                                                \
                for (int nj = 0; nj < 4; ++nj)                                   \
                    acc[mi][nj] = __builtin_amdgcn_mfma_f32_32x32x16_bf16(       \
                        AF[mi], BF[nj], acc[mi][nj], 0, 0, 0);                   \
        }

    bf16x8 aA[4], aB[4], bA[4], bB[4];
    LOAD_A(0, aA);                         // issue A(0) first (L2 latency hidden
                                           // under the transpose below)

    // ---- fused B-tile transpose+cast+swizzle ----
    const float* xb = x + (size_t)b * C_IN * LEN;
    {
        // phase 1: rows 0..127, one row per thread; lanes = consecutive l
        int r = t;
        int l = lbase + r - PAD;
        l = l < 0 ? 0 : (l > LEN - 1 ? LEN - 1 : l);
        int key = r & 15;
        float v[16][8];
        #pragma unroll
        for (int cb = 0; cb < 16; ++cb)
            #pragma unroll
            for (int e = 0; e < 8; ++e)
                v[cb][e] = xb[(size_t)(cb * 8 + e) * LEN + l];   // coalesced
        #pragma unroll
        for (int cb = 0; cb < 16; ++cb) {
            ushort8 u;
            #pragma unroll
            for (int e = 0; e < 8; ++e) u[e] = f2bf(v[cb][e]);
            *reinterpret_cast<ushort8*>(ldsx + r * 128 + ((cb ^ key) * 8)) = u;
        }
    }
    {
        // phase 2: halo rows 128..135, (row, cblk) unit per thread
        int r  = 128 + (t & 7);
        int cb = t >> 3;                   // 0..15
        int l = lbase + r - PAD;
        l = l < 0 ? 0 : (l > LEN - 1 ? LEN - 1 : l);
        ushort8 u;
        #pragma unroll
        for (int e = 0; e < 8; ++e)
            u[e] = f2bf(xb[(size_t)(cb * 8 + e) * LEN + l]);
        *reinterpret_cast<ushort8*>(ldsx + r * 128 + ((cb ^ (r & 15)) * 8)) = u;
    }
    __syncthreads();                       // B-tile ready; the only barrier

    f32x16 acc[4][4] = {};
    const char* ldsbase = reinterpret_cast<const char*>(ldsx);
    LOAD_B(0, bA);

    #pragma unroll 1
    for (int s = 0; s < NSTEP; s += 2) {   // ROLLED: compact 2-step body
        LOAD_A(s + 1, aB);
        LOAD_B(s + 1, bB);
        MFMA16(aA, bA);
        if (s + 2 < NSTEP) { LOAD_A(s + 2, aA); LOAD_B(s + 2, bA); }
        MFMA16(aB, bB);
    }

    // ---- epilogue: 32x32 D layout col = lane&31 (l), row = (reg&3)+8*(reg>>2)+4*hi
    #pragma unroll
    for (int mi = 0; mi < 4; ++mi) {
        int o0 = wm * 128 + mi * 32 + hi * 4;
        #pragma unroll
        for (int nj = 0; nj < 4; ++nj) {
            int l = lbase + nj * 32 + l31;
            #pragma unroll
            for (int q = 0; q < 4; ++q) {
                f32x4 eb = *reinterpret_cast<const f32x4*>(ebias + o0 + q * 8);
                float* op = out + (size_t)(b * C_OUT + o0 + q * 8) * LEN + l;
                #pragma unroll
                for (int p = 0; p < 4; ++p)
                    op[(size_t)p * LEN] = acc[mi][nj][q * 4 + p] + eb[p];
            }
        }
    }
    #undef LOAD_A
    #undef LOAD_B
    #undef MFMA16
}

extern "C" void kernel_launch(void* const* d_in, const int* in_sizes, int n_in,
                              void* d_out, int out_size, void* d_ws, size_t ws_size,
                              hipStream_t stream) {
    const float* x      = (const float*)d_in[0];
    const float* weight = (const float*)d_in[1];
    const float* bias   = (const float*)d_in[2];
    const float* vel    = (const float*)d_in[3];
    const float* acc    = (const float*)d_in[4];
    float* out = (float*)d_out;

    char* ws = (char*)d_ws;
    u16*  w5    = (u16*)ws;                                   // 589,824 B
    float* ebias = (float*)(ws + (size_t)C_OUT * KTOT * 2);

    hipLaunchKernelGGL(prep_all, dim3(W5_BLKS + EB_BLKS), dim3(256), 0, stream,
                       weight, bias, vel, acc, w5, ebias,
                       out + (size_t)BATCH * C_OUT * LEN);
    hipLaunchKernelGGL(conv_main, dim3(LEN / 128, BATCH), dim3(128), 0, stream,
                       x, w5, ebias, out);
}

// Round 17
// 54.044 us; speedup vs baseline: 2.3647x; 2.3647x over previous
//
#include <hip/hip_runtime.h>
#include <hip/hip_bf16.h>

typedef unsigned short u16;
typedef __bf16 bf16x8 __attribute__((ext_vector_type(8)));
typedef float f32x4 __attribute__((ext_vector_type(4)));
typedef float f32x16 __attribute__((ext_vector_type(16)));
typedef unsigned short ushort8 __attribute__((ext_vector_type(8)));

#define C_IN   128
#define C_OUT  256
#define BATCH  16
#define LEN    4096
#define KS     9
#define PAD    4
#define KTOT   (C_IN * KS)        // 1152
#define NSTEP  72                 // K = 1152 / 16

#define W5_BLKS    1152           // 294912 / 256
#define EB_BLKS    256

__device__ inline u16 f2bf(float f) {
    __hip_bfloat16 h = __float2bfloat16(f);
    return __builtin_bit_cast(u16, h);
}

// async global->LDS, 16B per lane, wave-uniform LDS base + lane*16
__device__ __forceinline__ void g2l16(const void* g, void* l) {
    __builtin_amdgcn_global_load_lds(
        (const __attribute__((address_space(1))) void*)g,
        (__attribute__((address_space(3))) void*)l, 16, 0, 0);
}

// ---------------------------------------------------------------------------
// Prep (unchanged): w5 repack + ebias + phys.
// ---------------------------------------------------------------------------
__global__ void prep_all(const float* __restrict__ w,
                         const float* __restrict__ bias, const float* __restrict__ vel,
                         const float* __restrict__ acc_in,
                         u16* __restrict__ w5,
                         float* __restrict__ ebias, float* __restrict__ phys_out) {
    int bid = blockIdx.x;
    int t = threadIdx.x;
    if (bid < W5_BLKS) {
        int i = bid * 256 + t;               // 294912 total
        int e    = i & 7;
        int lane = (i >> 3) & 63;
        int g    = (i >> 9) & 7;
        int s    = i >> 12;                  // 0..71
        int o    = g * 32 + (lane & 31);
        int hi   = lane >> 5;
        int c    = (s & 7) * 16 + hi * 8 + e;
        int k    = s >> 3;
        w5[i] = f2bf(w[((size_t)o * C_IN + c) * KS + k]);
        return;
    }
    __shared__ float red[256];
    int o = bid - W5_BLKS;
    float sum = 0.f;
    for (int i = t; i < KTOT; i += 256) {
        int k = i % KS;                    // offset layout [c][k]
        float tk = k * 0.01f;              // DT
        float off = vel[i] * tk + 0.5f * acc_in[i] * tk * tk;
        sum += off * w[(size_t)o * KTOT + i];
    }
    red[t] = sum;
    __syncthreads();
    for (int h = 128; h > 0; h >>= 1) {
        if (t < h) red[t] += red[t + h];
        __syncthreads();
    }
    if (t == 0) ebias[o] = bias[o] + red[0];

    if (o == 0) {                          // phys
        __syncthreads();
        float pv = 0.f;
        for (int i = t; i < KTOT; i += 256) {
            float v = vel[i], a = acc_in[i];
            pv += v * v + a * a;
        }
        red[t] = pv;
        __syncthreads();
        for (int h = 128; h > 0; h >>= 1) {
            if (t < h) red[t] += red[t + h];
            __syncthreads();
        }
        if (t == 0) *phys_out = 0.01f * (red[0] / (float)KTOT);
    }
}

// ---------------------------------------------------------------------------
// Main: m201-style PHASE-DISCIPLINED loop on R10 geometry + R15 fused parts.
// Block 256 thr / 4 waves (wm 0..1 x wn 0..1) = 256o x 128l; wave 128o x 64l
// (acc[4][2] f32x16 = 128 regs). A ring-4 x 8KB staged distance 3 via g2l16;
// B tile (136x256B) built once by fused transpose. LDS 66.8KB -> 2 blk/CU
// (staggered barriers; one block's MFMA covers the other's edges).
// Per step: {6 ds_read issue ; STAGE(s+3) issue ; vmcnt(4) [counted - never
// 0 mid-loop: leaves stage(s+2),(s+3) in flight] ; barrier ; lgkmcnt(0) +
// sched_barrier ; setprio(1) 8xMFMA_32x32 (270cyc cluster) setprio(0) ;
// barrier}. The barrier-pair FORCES the load-issue window before the MFMA
// window (R10-15's free-floating prefetch never achieved this - 41.5us
// plateau = 930TF = documented m97-class 2-phase ceiling).
// WAR safety: STAGE(s+3) writes slot (s-1)&3; its readers (step s-1) passed
// lgkmcnt(0) before MFMA(s-1), and barrier#2(s-1) orders ALL waves' reads
// before ANY wave's stage issue at step s. vmcnt before barrier + reads
// after barrier publishes landings cross-wave (m201 rule).
// ---------------------------------------------------------------------------
__global__ __launch_bounds__(256, 2) void conv_main(const float* __restrict__ x,
                                                    const u16* __restrict__ w5,
                                                    const float* __restrict__ ebias,
                                                    float* __restrict__ out) {
    __shared__ u16 ldsx[17408];            // B tile: 136 rows x 256B = 34816 B
    __shared__ u16 ldsa[4][4096];          // A ring: 4 x 8192 B

    int b     = blockIdx.y;
    int lbase = blockIdx.x * 128;
    int t     = threadIdx.x;               // 0..255
    int lane  = t & 63;
    int w     = t >> 6;                    // wave 0..3
    int wm    = w >> 1;                    // o-half
    int wn    = w & 1;                     // l-half
    int l31   = lane & 31;
    int hi    = lane >> 5;

    #define LOAD_A(SLOT, AF)                                                     \
        {                                                                        \
            const u16* ab_ = ldsa[SLOT] + (wm * 4) * 512 + lane * 8;             \
            _Pragma("unroll")                                                    \
            for (int mi = 0; mi < 4; ++mi)                                       \
                AF[mi] = *reinterpret_cast<const bf16x8*>(ab_ + mi * 512);       \
        }
    #define LOAD_B(S, BF)                                                        \
        {                                                                        \
            int k_ = (S) >> 3;                                                   \
            int sl_ = ((S) & 7) * 2 + hi;                                        \
            _Pragma("unroll")                                                    \
            for (int nj = 0; nj < 2; ++nj) {                                     \
                int row_  = wn * 64 + nj * 32 + l31 + k_;                        \
                int addr_ = row_ * 256 + ((sl_ ^ (row_ & 15)) << 4);             \
                BF[nj] = *reinterpret_cast<const bf16x8*>(ldsbase + addr_);      \
            }                                                                    \
        }
    #define STAGE_A(S)                                                           \
        {                                                                        \
            const u16* as_ = w5 + (size_t)(S) * 4096;                            \
            u16* ad_ = ldsa[(S) & 3];                                            \
            _Pragma("unroll")                                                    \
            for (int j = 0; j < 2; ++j)                                          \
                g2l16(as_ + (j * 256 + t) * 8, ad_ + (j * 256 + w * 64) * 8);    \
        }
    #define MFMA8(AF, BF)                                                        \
        {                                                                        \
            _Pragma("unroll")                                                    \
            for (int mi = 0; mi < 4; ++mi)                                       \
                _Pragma("unroll")                                                \
                for (int nj = 0; nj < 2; ++nj)                                   \
                    acc[mi][nj] = __builtin_amdgcn_mfma_f32_32x32x16_bf16(       \
                        AF[mi], BF[nj], acc[mi][nj], 0, 0, 0);                   \
        }

    // ---- prologue: fused transpose (B tile) + STAGE_A(0..2)
    const float* xb = x + (size_t)b * C_IN * LEN;
    {
        STAGE_A(0); STAGE_A(1); STAGE_A(2);
        if (t < 128) {
            // rows 0..127: one row per thread, 16 cb units, lanes->consecutive l
            int r = t;
            int l = lbase + r - PAD;
            l = l < 0 ? 0 : (l > LEN - 1 ? LEN - 1 : l);
            int key = r & 15;
            #pragma unroll
            for (int cb = 0; cb < 16; ++cb) {
                ushort8 u;
                #pragma unroll
                for (int e = 0; e < 8; ++e)
                    u[e] = f2bf(xb[(size_t)(cb * 8 + e) * LEN + l]);
                *reinterpret_cast<ushort8*>(ldsx + r * 128 + ((cb ^ key) * 8)) = u;
            }
        } else {
            // halo rows 128..135: (row, cb) unit per thread, 128 units exactly
            int u2 = t - 128;
            int r  = 128 + (u2 >> 4);
            int cb = u2 & 15;
            int l = lbase + r - PAD;
            l = l < 0 ? 0 : (l > LEN - 1 ? LEN - 1 : l);
            ushort8 u;
            #pragma unroll
            for (int e = 0; e < 8; ++e)
                u[e] = f2bf(xb[(size_t)(cb * 8 + e) * LEN + l]);
            *reinterpret_cast<ushort8*>(ldsx + r * 128 + ((cb ^ (r & 15)) * 8)) = u;
        }
    }
    // stage(0) landed (leave 1,2 in flight: 6 outstanding -> vmcnt(4));
    // ds_writes drained (lgkm0); barrier publishes both.
    asm volatile("s_waitcnt vmcnt(4) lgkmcnt(0)" ::: "memory");
    __builtin_amdgcn_s_barrier();

    f32x16 acc[4][2] = {};
    const char* ldsbase = reinterpret_cast<const char*>(ldsx);

    #pragma unroll
    for (int s = 0; s < NSTEP; ++s) {
        bf16x8 af[4], bf[2];
        LOAD_A(s & 3, af);                 // 4 ds_read (issue window)
        LOAD_B(s, bf);                     // 2 ds_read
        if (s + 3 < NSTEP) STAGE_A(s + 3); // 2 g2l16 (issue window)
        // counted vmcnt: stage(s+1) landed; (s+2),(s+3) stay in flight
        if (s + 3 < NSTEP)      asm volatile("s_waitcnt vmcnt(4)" ::: "memory");
        else if (s + 2 < NSTEP) asm volatile("s_waitcnt vmcnt(2)" ::: "memory");
        else                    asm volatile("s_waitcnt vmcnt(0)" ::: "memory");
        __builtin_amdgcn_s_barrier();
        asm volatile("s_waitcnt lgkmcnt(0)" ::: "memory");
        __builtin_amdgcn_sched_barrier(0);
        __builtin_amdgcn_s_setprio(1);
        MFMA8(af, bf);
        __builtin_amdgcn_s_setprio(0);
        if (s + 1 < NSTEP) __builtin_amdgcn_s_barrier();
    }

    // ---- epilogue: 32x32 D layout col = lane&31 (l), row = (reg&3)+8*(reg>>2)+4*hi
    #pragma unroll
    for (int mi = 0; mi < 4; ++mi) {
        int o0 = wm * 128 + mi * 32 + hi * 4;
        #pragma unroll
        for (int nj = 0; nj < 2; ++nj) {
            int l = lbase + wn * 64 + nj * 32 + l31;
            #pragma unroll
            for (int q = 0; q < 4; ++q) {
                f32x4 eb = *reinterpret_cast<const f32x4*>(ebias + o0 + q * 8);
                float* op = out + (size_t)(b * C_OUT + o0 + q * 8) * LEN + l;
                #pragma unroll
                for (int p = 0; p < 4; ++p)
                    op[(size_t)p * LEN] = acc[mi][nj][q * 4 + p] + eb[p];
            }
        }
    }
    #undef LOAD_A
    #undef LOAD_B
    #undef STAGE_A
    #undef MFMA8
}

extern "C" void kernel_launch(void* const* d_in, const int* in_sizes, int n_in,
                              void* d_out, int out_size, void* d_ws, size_t ws_size,
                              hipStream_t stream) {
    const float* x      = (const float*)d_in[0];
    const float* weight = (const float*)d_in[1];
    const float* bias   = (const float*)d_in[2];
    const float* vel    = (const float*)d_in[3];
    const float* acc    = (const float*)d_in[4];
    float* out = (float*)d_out;

    char* ws = (char*)d_ws;
    u16*  w5    = (u16*)ws;                                   // 589,824 B
    float* ebias = (float*)(ws + (size_t)C_OUT * KTOT * 2);

    hipLaunchKernelGGL(prep_all, dim3(W5_BLKS + EB_BLKS), dim3(256), 0, stream,
                       weight, bias, vel, acc, w5, ebias,
                       out + (size_t)BATCH * C_OUT * LEN);
    hipLaunchKernelGGL(conv_main, dim3(LEN / 128, BATCH), dim3(256), 0, stream,
                       x, w5, ebias, out);
}